// Round 6
// baseline (212.832 us; speedup 1.0000x reference)
//
#include <hip/hip_runtime.h>
#include <hip/hip_bf16.h>
#include <math.h>

// Shapes: B=4, N=1024, D=768, H=12, hd=64
constexpr int NSeq = 1024;
constexpr int DIM  = 768;
constexpr int NH   = 12;
constexpr int HD   = 64;

// exp2-domain softmax constants (BSHIFT removed: softmax is shift-invariant;
// args stay in [-17,+3], p <= ~10, f32 row-sums are safe)
#define LOG2E     1.4426950408889634f
#define QSCALE    0.18033688011112042f   /* 0.125 * log2e */
#define EBQ       6551.278150676693f     /* log2e * 4541 (16-bit quant scale) */
#define EBDEC     (-1.0f / 4541.0f)

#if __has_builtin(__builtin_amdgcn_exp2f)
#define EXP2F(x) __builtin_amdgcn_exp2f(x)
#else
#define EXP2F(x) exp2f(x)
#endif

typedef __attribute__((ext_vector_type(8))) short bf16x8;   // 8 bf16 (4 VGPRs)
typedef __attribute__((ext_vector_type(4))) float f32x4;

// fp32 -> bf16 RNE (scalar)
__device__ __forceinline__ short f2b(float f) {
    unsigned u = __float_as_uint(f);
    unsigned r = (u + 0x7fffu + ((u >> 16) & 1u)) >> 16;
    return (short)r;
}
// packed pair via native v_cvt_pk_bf16_f32
__device__ __forceinline__ unsigned pk2(float a, float b) {
    __hip_bfloat162 h = __float22bfloat162_rn(float2{a, b});
    return *reinterpret_cast<unsigned*>(&h);
}

// async global->LDS, 16B per lane. LDS dest = uniform base + lane*16.
__device__ __forceinline__ void glds16(const short* g, short* l) {
    __builtin_amdgcn_global_load_lds(
        (const __attribute__((address_space(1))) void*)g,
        (__attribute__((address_space(3))) void*)l, 16, 0, 0);
}

// T5 bucket, integer-exact thresholds (validated round 1)
__device__ __forceinline__ int rel_bucket(int rel) {
    int n = -rel;
    int ret = (n < 0) ? 16 : 0;
    n = (n < 0) ? -n : n;
    int k;
    if (n < 8) {
        k = n;
    } else {
        k = 8 + (n >= 12) + (n >= 16) + (n >= 23) + (n >= 32)
              + (n >= 46) + (n >= 64) + (n >= 91);
        if (k > 15) k = 15;
    }
    return ret + k;
}

// ---------------------------------------------------------------------------
// Fused prep (unchanged).
constexpr int PREP_UP   = 2048;
constexpr int PREP_CE   = PREP_UP + 3072;     // 5120 cast end
constexpr int PREP_TOT  = PREP_CE + 576;      // 5696

__global__ __launch_bounds__(256) void prep_kernel(
    const float* __restrict__ x, short* __restrict__ xb,
    const float* __restrict__ Wqkv, short* __restrict__ wqkvT,
    const float* __restrict__ Wproj, short* __restrict__ wprojT,
    const float* __restrict__ coords, const float* __restrict__ elev,
    const float* __restrict__ alpha_p, unsigned int* __restrict__ U)
{
    __shared__ float t[32][33];
    const int bx  = blockIdx.x;
    const int tid = threadIdx.x;

    if (bx < PREP_UP) {
        const int b    = bx >> 9;
        const int rem  = bx & 511;
        const int i16  = rem >> 3;
        const int jtp  = rem & 7;
        const int blk  = b * 64 + i16;
        const int lane = tid & 63, wv = tid >> 6;
        const int L = lane & 15, Q = lane >> 4;
        const float alpha = alpha_p[0];

        const int i = (i16 << 4) + L;
        const float2 cf = *(const float2*)&coords[(((size_t)b << 10) + i) * 2];
        const int cix = (int)(cf.x * 128.0f);
        const int ciy = (int)(cf.y * 128.0f);
        const float er = elev[((size_t)b << 10) + i];
        const int jt = jtp * 2 + (wv >> 1);
#pragma unroll
        for (int nth = 0; nth < 2; ++nth) {
            const int nt = (wv & 1) * 2 + nth;
            const int j0q = jt * 64 + nt * 16 + Q * 4;
            float4 c01 = *(const float4*)&coords[(((size_t)b << 10) + j0q) * 2];
            float4 c23 = *(const float4*)&coords[(((size_t)b << 10) + j0q + 2) * 2];
            float4 ej  = *(const float4*)&elev[((size_t)b << 10) + j0q];
            const float cjx[4] = {c01.x, c01.z, c23.x, c23.z};
            const float cjy[4] = {c01.y, c01.w, c23.y, c23.w};
            const float ejv[4] = {ej.x, ej.y, ej.z, ej.w};
            unsigned int uo[4];
#pragma unroll
            for (int reg = 0; reg < 4; ++reg) {
                int bk = rel_bucket(cix - (int)(cjx[reg] * 128.0f)) * 32
                       + rel_bucket(ciy - (int)(cjy[reg] * 128.0f));
                float ebp = fminf(10.0f,
                    fmaxf(0.0f, alpha * fmaxf((ejv[reg] - er) * 0.001f, 0.0f)));
                unsigned int q = (unsigned int)lrintf(ebp * EBQ);
                uo[reg] = (unsigned int)bk | (q << 16);
            }
            size_t base = ((((size_t)blk * 16 + jt) * 4 + nt) * 64 + lane) * 4;
            *(uint4*)(U + base) = make_uint4(uo[0], uo[1], uo[2], uo[3]);
        }
        return;
    }
    if (bx < PREP_CE) {
        int i = ((bx - PREP_UP) * 256 + tid) * 4;
        float4 v = *(const float4*)(x + i);
        *(short4*)(xb + i) = make_short4(f2b(v.x), f2b(v.y), f2b(v.z), f2b(v.w));
        return;
    }
    {
        const int bxx = bx - PREP_CE;          // 0..575
#pragma unroll
        for (int tt = 0; tt < 4; ++tt) {
            const int tile = bxx * 4 + tt;     // 0..2303
            const float* W; short* WT; int K, Nw, idx;
            if (tile < 1728) { W = Wqkv;  WT = wqkvT;  K = DIM; Nw = 3 * DIM; idx = tile; }
            else             { W = Wproj; WT = wprojT; K = DIM; Nw = DIM;     idx = tile - 1728; }
            const int ntl = idx % (Nw / 32), ktl = idx / (Nw / 32);
            const int k0 = ktl * 32, n0 = ntl * 32;
            const int tx = tid & 31, ty = tid >> 5;
            __syncthreads();                   // WAR vs previous tile's reads
#pragma unroll
            for (int r = 0; r < 4; ++r)
                t[ty + r * 8][tx] = W[(size_t)(k0 + ty + r * 8) * Nw + n0 + tx];
            __syncthreads();
#pragma unroll
            for (int r = 0; r < 4; ++r)
                WT[(size_t)(n0 + ty + r * 8) * K + k0 + tx] = f2b(t[tx][ty + r * 8]);
        }
    }
}

// ---------------------------------------------------------------------------
// bf16 MFMA GEMM (R3-verified form): C = A[M,K] @ BT[N,K]^T. Tile 64x128,
// BK=64, block 256 = 2x2 waves, wave tile 32x64. (BM=128 variant refuted R5:
// 576-block grid at 32KB LDS is residency-starved; no win at this shape.)
template <int EPI>
__global__ __launch_bounds__(256) void gemm_mfma(
    const short* __restrict__ A, const short* __restrict__ BT,
    const float* __restrict__ bias, float* __restrict__ Cout,
    short* __restrict__ qh, short* __restrict__ kh, short* __restrict__ vt,
    int M, int N, int K)
{
    __shared__ short SH[64 * 64 + 128 * 64];   // As (8 KB) | Bs (16 KB)
    short* As = SH;
    short* Bs = SH + 64 * 64;

    const int tid  = threadIdx.x;
    const int lane = tid & 63;
    const int wave = tid >> 6;
    const int L = lane & 15, Q = lane >> 4;
    const int m0b = blockIdx.y * 64, n0b = blockIdx.x * 128;
    const int mw = (wave >> 1) * 32;
    const int nw = (wave & 1) * 64;

    size_t aoff[2]; int la[2];
#pragma unroll
    for (int t = 0; t < 2; ++t) {
        int s = wave * 128 + t * 64 + lane;
        int r = s >> 3, c = (s & 7) ^ (r & 7);
        aoff[t] = (size_t)(m0b + r) * K + c * 8;
        la[t] = (wave * 128 + t * 64) * 8;
    }
    size_t boff[4]; int lb[4];
#pragma unroll
    for (int t = 0; t < 4; ++t) {
        int s = wave * 256 + t * 64 + lane;
        int r = s >> 3, c = (s & 7) ^ (r & 7);
        boff[t] = (size_t)(n0b + r) * K + c * 8;
        lb[t] = (wave * 256 + t * 64) * 8;
    }

    f32x4 acc[2][4];
#pragma unroll
    for (int i = 0; i < 2; ++i)
#pragma unroll
        for (int j = 0; j < 4; ++j) acc[i][j] = (f32x4){0.f, 0.f, 0.f, 0.f};

    for (int k0 = 0; k0 < K; k0 += 64) {
        __syncthreads();
#pragma unroll
        for (int t = 0; t < 2; ++t) glds16(A + aoff[t] + k0, As + la[t]);
#pragma unroll
        for (int t = 0; t < 4; ++t) glds16(BT + boff[t] + k0, Bs + lb[t]);
        __syncthreads();
#pragma unroll
        for (int ks = 0; ks < 2; ++ks) {
            bf16x8 af[2], bfr[4];
#pragma unroll
            for (int mt = 0; mt < 2; ++mt) {
                int r = mw + mt * 16 + L;
                af[mt] = *(const bf16x8*)(As + (r * 8 + ((ks * 4 + Q) ^ (r & 7))) * 8);
            }
#pragma unroll
            for (int nt = 0; nt < 4; ++nt) {
                int r = nw + nt * 16 + L;
                bfr[nt] = *(const bf16x8*)(Bs + (r * 8 + ((ks * 4 + Q) ^ (r & 7))) * 8);
            }
#pragma unroll
            for (int mt = 0; mt < 2; ++mt)
#pragma unroll
                for (int nt = 0; nt < 4; ++nt)
                    acc[mt][nt] = __builtin_amdgcn_mfma_f32_16x16x32_bf16(
                        af[mt], bfr[nt], acc[mt][nt], 0, 0, 0);
        }
    }

    const int m0 = m0b + mw, n0 = n0b + nw;
    if (EPI == 1) {
#pragma unroll
        for (int nt = 0; nt < 4; ++nt) {
            const int col = n0 + nt * 16 + L;
            const float bv = bias[col];
#pragma unroll
            for (int mt = 0; mt < 2; ++mt) {
                const int r0 = m0 + mt * 16 + Q * 4;
#pragma unroll
                for (int reg = 0; reg < 4; ++reg)
                    Cout[(size_t)(r0 + reg) * N + col] = acc[mt][nt][reg] + bv;
            }
        }
    } else {
        // ---- EPI=0: LDS-staged coalesced scatter.
        const int sec   = n0b / DIM;          // 0=Q, 1=K, 2=V
        const int hloc  = (n0b % DIM) >> 6;   // tile spans heads hloc, hloc+1
        const int bidx  = m0b >> 10;
        const int ntok0 = m0b & 1023;
        short* T = SH;
        __syncthreads();                      // all LDS reads of K-loop done

        if (sec < 2) {
            // T[token][col], stride 136
            const float qs = (sec == 0) ? QSCALE : 1.0f;
#pragma unroll
            for (int nt = 0; nt < 4; ++nt)
#pragma unroll
                for (int mt = 0; mt < 2; ++mt) {
                    int tok = mw + mt * 16 + Q * 4;
                    int col = nw + nt * 16 + L;
#pragma unroll
                    for (int reg = 0; reg < 4; ++reg)
                        T[(tok + reg) * 136 + col] = f2b(acc[mt][nt][reg] * qs);
                }
            __syncthreads();
            const int pr = tid >> 1, half = tid & 1;
            const int hh = pr >> 6, tok = pr & 63;
            short* dstb = (sec == 0 ? qh : kh)
                + (((size_t)bidx * NH + hloc + hh) * NSeq + ntok0 + tok) * HD + half * 32;
            const short* srcb = T + tok * 136 + hh * 64 + half * 32;
#pragma unroll
            for (int c = 0; c < 4; ++c)
                *(bf16x8*)(dstb + c * 8) = *(const bf16x8*)(srcb + c * 8);
        } else {
            // V: T[col][token], stride 72; packed 8B frag writes
#pragma unroll
            for (int nt = 0; nt < 4; ++nt)
#pragma unroll
                for (int mt = 0; mt < 2; ++mt) {
                    int tok = mw + mt * 16 + Q * 4;
                    int col = nw + nt * 16 + L;
                    short4 pv = make_short4(f2b(acc[mt][nt][0]), f2b(acc[mt][nt][1]),
                                            f2b(acc[mt][nt][2]), f2b(acc[mt][nt][3]));
                    *(short4*)&T[col * 72 + tok] = pv;
                }
            __syncthreads();
            const int col = tid >> 1, half = tid & 1;
            const int hh = col >> 6, d = col & 63;
            short* dstb = vt
                + (((size_t)bidx * NH + hloc + hh) * HD + d) * NSeq + ntok0 + half * 32;
            const short* srcb = T + col * 72 + half * 32;
#pragma unroll
            for (int c = 0; c < 4; ++c)
                *(bf16x8*)(dstb + c * 8) = *(const bf16x8*)(srcb + c * 8);
        }
    }
}

// ---------------------------------------------------------------------------
// Transposed-S flash attention, v10: v9 + T14 async-STAGE split.
// v9 staged K/V via glds16 between two barriers -> vmcnt(0) drain exposed
// ~600cy HBM latency every jt. v10: issue next-tile loads into REGISTERS at
// the top of the iteration (latency hides under QK/exp/PV), then barrier +
// ds_write + barrier. Global addresses carry the XOR swizzle, so LDS writes
// stay linear (lsl[t]) and all read paths are unchanged. kreg/vreg lifetime
// is confined to one iteration (+32 VGPR, no R2-style cross-iter buffer).
__global__ __launch_bounds__(256, 3) void attn_mfma(
    const short* __restrict__ qh, const short* __restrict__ kh,
    const short* __restrict__ vt,
    const unsigned int* __restrict__ U,
    const float* __restrict__ btab_g,             // [1024][12]
    short* __restrict__ aout)                     // [4096][768] bf16
{
    __shared__ short Ks[128 * 64];      // 16 KB, rows=j (128), 8 chunks/row
    __shared__ short Vs[64 * 128];      // 16 KB, rows=d (64), 16 chunks/row
    __shared__ float btab[1024];        // 4 KB (pre-scaled: *log2e)
    __shared__ short P[4][2][16 * 64];  // 16 KB: [wave][it][row L][64]

    const int tid   = threadIdx.x;
    const int lane  = tid & 63, wave = tid >> 6;
    const int iHalf = wave >> 1, jHalf = wave & 1;
    const int L = lane & 15, Q = lane >> 4;
    const int i0 = blockIdx.x * 64;
    const int bh = blockIdx.y;
    const int b  = bh / NH, h = bh % NH;

    for (int p = tid; p < 1024; p += 256)
        btab[p] = btab_g[(size_t)p * NH + h] * LOG2E;

    const int iw = i0 + iHalf * 32;
    bf16x8 qf[2][2];
#pragma unroll
    for (int it = 0; it < 2; ++it) {
        const short* qb = qh + ((size_t)bh * NSeq + iw + it * 16 + L) * HD + Q * 8;
        qf[it][0] = *(const bf16x8*)qb;
        qf[it][1] = *(const bf16x8*)(qb + 32);
    }

    size_t kgo[4], vgo[4];
    int lsl[4];
#pragma unroll
    for (int t = 0; t < 4; ++t) {
        int s = wave * 256 + t * 64 + lane;            // 0..1023
        int kr = s >> 3, kc = (s & 7) ^ (kr & 7);
        kgo[t] = ((size_t)bh * NSeq + kr) * HD + kc * 8;       // + j0*HD
        int vr = s >> 4, vc = (s & 15) ^ (vr & 15);
        vgo[t] = ((size_t)bh * HD + vr) * NSeq + vc * 8;       // + j0
        lsl[t] = s * 8;
    }

    const int i16g0 = b * 64 + blockIdx.x * 4 + iHalf * 2;
    const unsigned int* Ub[2] = {
        U + (size_t)i16g0 * 16 * 4 * 256 + lane * 4,
        U + ((size_t)i16g0 + 1) * 16 * 4 * 256 + lane * 4 };

    float lpart[2] = {0.0f, 0.0f};
    f32x4 accO[2][4];
#pragma unroll
    for (int it = 0; it < 2; ++it)
#pragma unroll
        for (int dt = 0; dt < 4; ++dt) accO[it][dt] = (f32x4){0.f, 0.f, 0.f, 0.f};

    const int swzB = (L & 7) << 4;      // XOR-16B chunk swizzle within 128B row

    // ---- prologue: fill tile 0 via async glds16 (one-time drain is fine;
    // this barrier also publishes btab)
#pragma unroll
    for (int t = 0; t < 4; ++t) glds16(kh + kgo[t], Ks + lsl[t]);
#pragma unroll
    for (int t = 0; t < 4; ++t) glds16(vt + vgo[t], Vs + lsl[t]);
    __syncthreads();

    for (int jt = 0; jt < 8; ++jt) {
        const int jt2 = jt * 2 + jHalf;        // 64-wide j-chunk index in U

        // T14: issue next-tile global loads into registers NOW; consumed
        // after the compute below, so HBM latency hides under QK/exp/PV.
        uint4 kreg[4], vreg[4];
        if (jt < 7) {
            const int j1 = (jt + 1) * 128;
#pragma unroll
            for (int t = 0; t < 4; ++t)
                kreg[t] = *(const uint4*)(kh + kgo[t] + (size_t)j1 * HD);
#pragma unroll
            for (int t = 0; t < 4; ++t)
                vreg[t] = *(const uint4*)(vt + vgo[t] + j1);
        }

        // QK^T + bias + exp2 + P-write for both i-subtiles (kf shared)
#pragma unroll
        for (int nt = 0; nt < 4; ++nt) {
            const int r = jHalf * 64 + nt * 16 + L;
            bf16x8 kf0 = *(const bf16x8*)(Ks + (r * 8 + (Q ^ (L & 7))) * 8);
            bf16x8 kf1 = *(const bf16x8*)(Ks + (r * 8 + ((4 + Q) ^ (L & 7))) * 8);
#pragma unroll
            for (int it = 0; it < 2; ++it) {
                f32x4 z = (f32x4){0.f, 0.f, 0.f, 0.f};
                z = __builtin_amdgcn_mfma_f32_16x16x32_bf16(kf0, qf[it][0], z, 0, 0, 0);
                f32x4 st = __builtin_amdgcn_mfma_f32_16x16x32_bf16(kf1, qf[it][1], z, 0, 0, 0);

                uint4 u = *(const uint4*)(Ub[it] + ((size_t)jt2 * 4 + nt) * 256);
                const unsigned int uv[4] = {u.x, u.y, u.z, u.w};
                float pv[4];
                float ps = 0.0f;
#pragma unroll
                for (int reg = 0; reg < 4; ++reg) {
                    float arg = st[reg] + btab[uv[reg] & 1023];
                    arg = fmaf((float)(uv[reg] >> 16), EBDEC, arg);
                    float pe = EXP2F(arg);
                    ps += pe;
                    pv[reg] = pe;
                }
                lpart[it] += ps;
                unsigned p01 = pk2(pv[0], pv[1]);
                unsigned p23 = pk2(pv[2], pv[3]);
                char* pw = (char*)(&P[wave][it][0]) + L * 128
                         + ((nt * 32 + Q * 8) ^ swzB);
                *(uint2*)pw = make_uint2(p01, p23);
            }
        }

        // PV: vf shared across both i-subtiles
        bf16x8 pf0[2], pf1[2];
#pragma unroll
        for (int it = 0; it < 2; ++it) {
            const char* pb = (const char*)(&P[wave][it][0]) + L * 128;
            pf0[it] = *(const bf16x8*)(pb + ((Q * 16) ^ swzB));
            pf1[it] = *(const bf16x8*)(pb + (((4 + Q) * 16) ^ swzB));
        }
        __builtin_amdgcn_s_setprio(1);
#pragma unroll
        for (int dt = 0; dt < 4; ++dt) {
            int r = dt * 16 + L;
            bf16x8 vf0 = *(const bf16x8*)(Vs + (r * 16 + ((jHalf * 8 + Q) ^ L)) * 8);
            bf16x8 vf1 = *(const bf16x8*)(Vs + (r * 16 + ((jHalf * 8 + 4 + Q) ^ L)) * 8);
            accO[0][dt] = __builtin_amdgcn_mfma_f32_16x16x32_bf16(pf0[0], vf0, accO[0][dt], 0, 0, 0);
            accO[0][dt] = __builtin_amdgcn_mfma_f32_16x16x32_bf16(pf1[0], vf1, accO[0][dt], 0, 0, 0);
            accO[1][dt] = __builtin_amdgcn_mfma_f32_16x16x32_bf16(pf0[1], vf0, accO[1][dt], 0, 0, 0);
            accO[1][dt] = __builtin_amdgcn_mfma_f32_16x16x32_bf16(pf1[1], vf1, accO[1][dt], 0, 0, 0);
        }
        __builtin_amdgcn_s_setprio(0);

        // write-late half of the T14 split: publish tile jt+1
        if (jt < 7) {
            __syncthreads();                 // all waves done reading tile jt
#pragma unroll
            for (int t = 0; t < 4; ++t) *(uint4*)(Ks + lsl[t]) = kreg[t];
#pragma unroll
            for (int t = 0; t < 4; ++t) *(uint4*)(Vs + lsl[t]) = vreg[t];
            __syncthreads();                 // tile jt+1 visible
        }
    }

    // ---- cross-jHalf reduction through the dead K/V buffers
    __syncthreads();
    float* Rac = (float*)Ks;    // [iHalf][it][dt][lane] f32x4 = 16 KB
    float* Rlp = (float*)Vs;    // [iHalf][it][lane] f32 = 1 KB
    if (jHalf == 1) {
#pragma unroll
        for (int it = 0; it < 2; ++it) {
#pragma unroll
            for (int dt = 0; dt < 4; ++dt)
                *(f32x4*)(Rac + (size_t)(((iHalf * 2 + it) * 4 + dt) * 64 + lane) * 4)
                    = accO[it][dt];
            Rlp[(iHalf * 2 + it) * 64 + lane] = lpart[it];
        }
    }
    __syncthreads();
    if (jHalf == 0) {
#pragma unroll
        for (int it = 0; it < 2; ++it) {
#pragma unroll
            for (int dt = 0; dt < 4; ++dt)
                accO[it][dt] += *(const f32x4*)(
                    Rac + (size_t)(((iHalf * 2 + it) * 4 + dt) * 64 + lane) * 4);
            float lp = lpart[it] + Rlp[(iHalf * 2 + it) * 64 + lane];
            lp += __shfl_xor(lp, 16, 64);
            lp += __shfl_xor(lp, 32, 64);
            float linv[4];
#pragma unroll
            for (int reg = 0; reg < 4; ++reg)
                linv[reg] = 1.0f / __shfl(lp, Q * 4 + reg, 64);
#pragma unroll
            for (int reg = 0; reg < 4; ++reg) {
                const size_t row = (size_t)b * NSeq + iw + it * 16 + Q * 4 + reg;
#pragma unroll
                for (int dt = 0; dt < 4; ++dt)
                    aout[row * DIM + h * HD + dt * 16 + L]
                        = f2b(accO[it][dt][reg] * linv[reg]);
            }
        }
    }
}

// ---------------------------------------------------------------------------
extern "C" void kernel_launch(void* const* d_in, const int* in_sizes, int n_in,
                              void* d_out, int out_size, void* d_ws, size_t ws_size,
                              hipStream_t stream)
{
    const float* x      = (const float*)d_in[0];
    const float* coords = (const float*)d_in[1];
    const float* elevp  = (const float*)d_in[2];
    const float* Wqkv   = (const float*)d_in[3];
    const float* Wproj  = (const float*)d_in[4];
    const float* bproj  = (const float*)d_in[5];
    const float* btab   = (const float*)d_in[6];
    const float* alpha  = (const float*)d_in[7];
    float* out = (float*)d_out;

    char* ws = (char*)d_ws;
    short* xb     = (short*)(ws);                        // 4096x768 bf16
    short* wqkvT  = (short*)(ws + 6291456);              // 2304x768 bf16
    short* wprojT = (short*)(ws + 9830400);              // 768x768 bf16
    short* qh     = (short*)(ws + 11010048);             // [48][1024][64]
    short* kh     = (short*)(ws + 17301504);
    short* vt     = (short*)(ws + 23592960);             // [48][64][1024]
    short* aout   = (short*)(ws + 29884416);             // 4096x768 bf16
    unsigned int* U = (unsigned int*)(ws + 36175872);    // 16.78 MB packed bias
    // total ws use: 52,953,088 bytes

    const int M = 4 * NSeq;

    prep_kernel<<<dim3(PREP_TOT), 256, 0, stream>>>(
        x, xb, Wqkv, wqkvT, Wproj, wprojT, coords, elevp, alpha, U);

    gemm_mfma<0><<<dim3(3 * DIM / 128, M / 64), 256, 0, stream>>>(
        xb, wqkvT, nullptr, nullptr, qh, kh, vt, M, 3 * DIM, DIM);

    attn_mfma<<<dim3(NSeq / 64, 4 * NH), 256, 0, stream>>>(
        qh, kh, vt, U, btab, aout);

    gemm_mfma<1><<<dim3(DIM / 128, M / 64), 256, 0, stream>>>(
        aout, wprojT, bproj, out, nullptr, nullptr, nullptr, M, DIM, DIM);
}

// Round 7
// 172.879 us; speedup vs baseline: 1.2311x; 1.2311x over previous
//
#include <hip/hip_runtime.h>
#include <hip/hip_bf16.h>
#include <math.h>

// Shapes: B=4, N=1024, D=768, H=12, hd=64
constexpr int NSeq = 1024;
constexpr int DIM  = 768;
constexpr int NH   = 12;
constexpr int HD   = 64;

// exp2-domain softmax constants (BSHIFT removed: softmax is shift-invariant;
// args stay in [-17,+3], p <= ~10, f32 row-sums are safe)
#define LOG2E     1.4426950408889634f
#define QSCALE    0.18033688011112042f   /* 0.125 * log2e */
#define EBQ       6551.278150676693f     /* log2e * 4541 (16-bit quant scale) */
#define EBDEC     (-1.0f / 4541.0f)

#if __has_builtin(__builtin_amdgcn_exp2f)
#define EXP2F(x) __builtin_amdgcn_exp2f(x)
#else
#define EXP2F(x) exp2f(x)
#endif

typedef __attribute__((ext_vector_type(8))) short bf16x8;   // 8 bf16 (4 VGPRs)
typedef __attribute__((ext_vector_type(4))) float f32x4;

// fp32 -> bf16 RNE (scalar)
__device__ __forceinline__ short f2b(float f) {
    unsigned u = __float_as_uint(f);
    unsigned r = (u + 0x7fffu + ((u >> 16) & 1u)) >> 16;
    return (short)r;
}
// packed pair via native v_cvt_pk_bf16_f32
__device__ __forceinline__ unsigned pk2(float a, float b) {
    __hip_bfloat162 h = __float22bfloat162_rn(float2{a, b});
    return *reinterpret_cast<unsigned*>(&h);
}

// async global->LDS, 16B per lane. LDS dest = uniform base + lane*16.
__device__ __forceinline__ void glds16(const short* g, short* l) {
    __builtin_amdgcn_global_load_lds(
        (const __attribute__((address_space(1))) void*)g,
        (__attribute__((address_space(3))) void*)l, 16, 0, 0);
}

// T5 bucket, integer-exact thresholds (validated round 1)
__device__ __forceinline__ int rel_bucket(int rel) {
    int n = -rel;
    int ret = (n < 0) ? 16 : 0;
    n = (n < 0) ? -n : n;
    int k;
    if (n < 8) {
        k = n;
    } else {
        k = 8 + (n >= 12) + (n >= 16) + (n >= 23) + (n >= 32)
              + (n >= 46) + (n >= 64) + (n >= 91);
        if (k > 15) k = 15;
    }
    return ret + k;
}

// ---------------------------------------------------------------------------
// Fused prep (unchanged).
constexpr int PREP_UP   = 2048;
constexpr int PREP_CE   = PREP_UP + 3072;     // 5120 cast end
constexpr int PREP_TOT  = PREP_CE + 576;      // 5696

__global__ __launch_bounds__(256) void prep_kernel(
    const float* __restrict__ x, short* __restrict__ xb,
    const float* __restrict__ Wqkv, short* __restrict__ wqkvT,
    const float* __restrict__ Wproj, short* __restrict__ wprojT,
    const float* __restrict__ coords, const float* __restrict__ elev,
    const float* __restrict__ alpha_p, unsigned int* __restrict__ U)
{
    __shared__ float t[32][33];
    const int bx  = blockIdx.x;
    const int tid = threadIdx.x;

    if (bx < PREP_UP) {
        const int b    = bx >> 9;
        const int rem  = bx & 511;
        const int i16  = rem >> 3;
        const int jtp  = rem & 7;
        const int blk  = b * 64 + i16;
        const int lane = tid & 63, wv = tid >> 6;
        const int L = lane & 15, Q = lane >> 4;
        const float alpha = alpha_p[0];

        const int i = (i16 << 4) + L;
        const float2 cf = *(const float2*)&coords[(((size_t)b << 10) + i) * 2];
        const int cix = (int)(cf.x * 128.0f);
        const int ciy = (int)(cf.y * 128.0f);
        const float er = elev[((size_t)b << 10) + i];
        const int jt = jtp * 2 + (wv >> 1);
#pragma unroll
        for (int nth = 0; nth < 2; ++nth) {
            const int nt = (wv & 1) * 2 + nth;
            const int j0q = jt * 64 + nt * 16 + Q * 4;
            float4 c01 = *(const float4*)&coords[(((size_t)b << 10) + j0q) * 2];
            float4 c23 = *(const float4*)&coords[(((size_t)b << 10) + j0q + 2) * 2];
            float4 ej  = *(const float4*)&elev[((size_t)b << 10) + j0q];
            const float cjx[4] = {c01.x, c01.z, c23.x, c23.z};
            const float cjy[4] = {c01.y, c01.w, c23.y, c23.w};
            const float ejv[4] = {ej.x, ej.y, ej.z, ej.w};
            unsigned int uo[4];
#pragma unroll
            for (int reg = 0; reg < 4; ++reg) {
                int bk = rel_bucket(cix - (int)(cjx[reg] * 128.0f)) * 32
                       + rel_bucket(ciy - (int)(cjy[reg] * 128.0f));
                float ebp = fminf(10.0f,
                    fmaxf(0.0f, alpha * fmaxf((ejv[reg] - er) * 0.001f, 0.0f)));
                unsigned int q = (unsigned int)lrintf(ebp * EBQ);
                uo[reg] = (unsigned int)bk | (q << 16);
            }
            size_t base = ((((size_t)blk * 16 + jt) * 4 + nt) * 64 + lane) * 4;
            *(uint4*)(U + base) = make_uint4(uo[0], uo[1], uo[2], uo[3]);
        }
        return;
    }
    if (bx < PREP_CE) {
        int i = ((bx - PREP_UP) * 256 + tid) * 4;
        float4 v = *(const float4*)(x + i);
        *(short4*)(xb + i) = make_short4(f2b(v.x), f2b(v.y), f2b(v.z), f2b(v.w));
        return;
    }
    {
        const int bxx = bx - PREP_CE;          // 0..575
#pragma unroll
        for (int tt = 0; tt < 4; ++tt) {
            const int tile = bxx * 4 + tt;     // 0..2303
            const float* W; short* WT; int K, Nw, idx;
            if (tile < 1728) { W = Wqkv;  WT = wqkvT;  K = DIM; Nw = 3 * DIM; idx = tile; }
            else             { W = Wproj; WT = wprojT; K = DIM; Nw = DIM;     idx = tile - 1728; }
            const int ntl = idx % (Nw / 32), ktl = idx / (Nw / 32);
            const int k0 = ktl * 32, n0 = ntl * 32;
            const int tx = tid & 31, ty = tid >> 5;
            __syncthreads();                   // WAR vs previous tile's reads
#pragma unroll
            for (int r = 0; r < 4; ++r)
                t[ty + r * 8][tx] = W[(size_t)(k0 + ty + r * 8) * Nw + n0 + tx];
            __syncthreads();
#pragma unroll
            for (int r = 0; r < 4; ++r)
                WT[(size_t)(n0 + ty + r * 8) * K + k0 + tx] = f2b(t[tx][ty + r * 8]);
        }
    }
}

// ---------------------------------------------------------------------------
// bf16 MFMA GEMM, 2-phase double-buffered (T3 minimum recipe, m248v2):
// issue next K-tile's glds16 BEFORE computing the current tile, ONE barrier
// per K-step. The compiler's mandatory vmcnt(0)-before-barrier then lands
// after 16 MFMAs + 12 ds_reads of compute instead of right after issue, so
// the ~600cy stage latency is hidden. (Old form: stage -> barrier -> compute
// -> barrier = latency fully exposed 12x/block.) LDS 48 KB -> 3 blocks/CU.
// Tile 64x128, BK=64, 2x2 waves, wave tile 32x64 (BM=128 refuted R5).
template <int EPI>
__global__ __launch_bounds__(256) void gemm_mfma(
    const short* __restrict__ A, const short* __restrict__ BT,
    const float* __restrict__ bias, float* __restrict__ Cout,
    short* __restrict__ qh, short* __restrict__ kh, short* __restrict__ vt,
    int M, int N, int K)
{
    // [buf][As 4096 | Bs 8192] shorts; 2 x 12288 = 48 KB
    __shared__ short SH[2 * (64 * 64 + 128 * 64)];

    const int tid  = threadIdx.x;
    const int lane = tid & 63;
    const int wave = tid >> 6;
    const int L = lane & 15, Q = lane >> 4;
    const int m0b = blockIdx.y * 64, n0b = blockIdx.x * 128;
    const int mw = (wave >> 1) * 32;
    const int nw = (wave & 1) * 64;

    size_t aoff[2]; int la[2];
#pragma unroll
    for (int t = 0; t < 2; ++t) {
        int s = wave * 128 + t * 64 + lane;
        int r = s >> 3, c = (s & 7) ^ (r & 7);
        aoff[t] = (size_t)(m0b + r) * K + c * 8;
        la[t] = (wave * 128 + t * 64) * 8;
    }
    size_t boff[4]; int lb[4];
#pragma unroll
    for (int t = 0; t < 4; ++t) {
        int s = wave * 256 + t * 64 + lane;
        int r = s >> 3, c = (s & 7) ^ (r & 7);
        boff[t] = (size_t)(n0b + r) * K + c * 8;
        lb[t] = (wave * 256 + t * 64) * 8;
    }

    f32x4 acc[2][4];
#pragma unroll
    for (int i = 0; i < 2; ++i)
#pragma unroll
        for (int j = 0; j < 4; ++j) acc[i][j] = (f32x4){0.f, 0.f, 0.f, 0.f};

    // prologue: stage tile 0 into buf 0
#pragma unroll
    for (int t = 0; t < 2; ++t) glds16(A + aoff[t], SH + la[t]);
#pragma unroll
    for (int t = 0; t < 4; ++t) glds16(BT + boff[t], SH + 4096 + lb[t]);
    __syncthreads();

    for (int k0 = 0; k0 < K; k0 += 64) {
        const int cur = (k0 >> 6) & 1;
        short* Asc = SH + cur * 12288;
        short* Bsc = Asc + 4096;

        // stage NEXT tile into the other buffer (issue-early; latency hides
        // under the compute below, drained by the end-of-iter barrier)
        if (k0 + 64 < K) {
            short* Asn = SH + (cur ^ 1) * 12288;
            short* Bsn = Asn + 4096;
#pragma unroll
            for (int t = 0; t < 2; ++t) glds16(A + aoff[t] + k0 + 64, Asn + la[t]);
#pragma unroll
            for (int t = 0; t < 4; ++t) glds16(BT + boff[t] + k0 + 64, Bsn + lb[t]);
        }

#pragma unroll
        for (int ks = 0; ks < 2; ++ks) {
            bf16x8 af[2], bfr[4];
#pragma unroll
            for (int mt = 0; mt < 2; ++mt) {
                int r = mw + mt * 16 + L;
                af[mt] = *(const bf16x8*)(Asc + (r * 8 + ((ks * 4 + Q) ^ (r & 7))) * 8);
            }
#pragma unroll
            for (int nt = 0; nt < 4; ++nt) {
                int r = nw + nt * 16 + L;
                bfr[nt] = *(const bf16x8*)(Bsc + (r * 8 + ((ks * 4 + Q) ^ (r & 7))) * 8);
            }
#pragma unroll
            for (int mt = 0; mt < 2; ++mt)
#pragma unroll
                for (int nt = 0; nt < 4; ++nt)
                    acc[mt][nt] = __builtin_amdgcn_mfma_f32_16x16x32_bf16(
                        af[mt], bfr[nt], acc[mt][nt], 0, 0, 0);
        }
        __syncthreads();   // drains next-tile stage (after compute) + WAR
    }

    const int m0 = m0b + mw, n0 = n0b + nw;
    if (EPI == 1) {
#pragma unroll
        for (int nt = 0; nt < 4; ++nt) {
            const int col = n0 + nt * 16 + L;
            const float bv = bias[col];
#pragma unroll
            for (int mt = 0; mt < 2; ++mt) {
                const int r0 = m0 + mt * 16 + Q * 4;
#pragma unroll
                for (int reg = 0; reg < 4; ++reg)
                    Cout[(size_t)(r0 + reg) * N + col] = acc[mt][nt][reg] + bv;
            }
        }
    } else {
        // ---- EPI=0: LDS-staged coalesced scatter (unchanged; T = SH).
        const int sec   = n0b / DIM;          // 0=Q, 1=K, 2=V
        const int hloc  = (n0b % DIM) >> 6;   // tile spans heads hloc, hloc+1
        const int bidx  = m0b >> 10;
        const int ntok0 = m0b & 1023;
        short* T = SH;
        // loop's final __syncthreads already ordered all K-loop LDS reads

        if (sec < 2) {
            // T[token][col], stride 136
            const float qs = (sec == 0) ? QSCALE : 1.0f;
#pragma unroll
            for (int nt = 0; nt < 4; ++nt)
#pragma unroll
                for (int mt = 0; mt < 2; ++mt) {
                    int tok = mw + mt * 16 + Q * 4;
                    int col = nw + nt * 16 + L;
#pragma unroll
                    for (int reg = 0; reg < 4; ++reg)
                        T[(tok + reg) * 136 + col] = f2b(acc[mt][nt][reg] * qs);
                }
            __syncthreads();
            const int pr = tid >> 1, half = tid & 1;
            const int hh = pr >> 6, tok = pr & 63;
            short* dstb = (sec == 0 ? qh : kh)
                + (((size_t)bidx * NH + hloc + hh) * NSeq + ntok0 + tok) * HD + half * 32;
            const short* srcb = T + tok * 136 + hh * 64 + half * 32;
#pragma unroll
            for (int c = 0; c < 4; ++c)
                *(bf16x8*)(dstb + c * 8) = *(const bf16x8*)(srcb + c * 8);
        } else {
            // V: T[col][token], stride 72; packed 8B frag writes
#pragma unroll
            for (int nt = 0; nt < 4; ++nt)
#pragma unroll
                for (int mt = 0; mt < 2; ++mt) {
                    int tok = mw + mt * 16 + Q * 4;
                    int col = nw + nt * 16 + L;
                    short4 pv = make_short4(f2b(acc[mt][nt][0]), f2b(acc[mt][nt][1]),
                                            f2b(acc[mt][nt][2]), f2b(acc[mt][nt][3]));
                    *(short4*)&T[col * 72 + tok] = pv;
                }
            __syncthreads();
            const int col = tid >> 1, half = tid & 1;
            const int hh = col >> 6, d = col & 63;
            short* dstb = vt
                + (((size_t)bidx * NH + hloc + hh) * HD + d) * NSeq + ntok0 + half * 32;
            const short* srcb = T + col * 72 + half * 32;
#pragma unroll
            for (int c = 0; c < 4; ++c)
                *(bf16x8*)(dstb + c * 8) = *(const bf16x8*)(srcb + c * 8);
        }
    }
}

// ---------------------------------------------------------------------------
// Transposed-S flash attention, v9 (R3-verified, 46.0 us): i-register-blocked
// 2x, conflict-minimal P layout (stride 128B + XOR(L&7) 16B-chunk swizzle),
// f32 btab, in-loop U loads, glds16 staging between two barriers.
// Reg-staging of K/V refuted twice (R2: VGPR dbuf spilled; R6: allocator put
// per-iter uint4 arrays in scratch, WRITE 6->178 MB). Do not re-attempt.
__global__ __launch_bounds__(256, 3) void attn_mfma(
    const short* __restrict__ qh, const short* __restrict__ kh,
    const short* __restrict__ vt,
    const unsigned int* __restrict__ U,
    const float* __restrict__ btab_g,             // [1024][12]
    short* __restrict__ aout)                     // [4096][768] bf16
{
    __shared__ short Ks[128 * 64];      // 16 KB, rows=j (128), 8 chunks/row
    __shared__ short Vs[64 * 128];      // 16 KB, rows=d (64), 16 chunks/row
    __shared__ float btab[1024];        // 4 KB (pre-scaled: *log2e)
    __shared__ short P[4][2][16 * 64];  // 16 KB: [wave][it][row L][64]

    const int tid   = threadIdx.x;
    const int lane  = tid & 63, wave = tid >> 6;
    const int iHalf = wave >> 1, jHalf = wave & 1;
    const int L = lane & 15, Q = lane >> 4;
    const int i0 = blockIdx.x * 64;
    const int bh = blockIdx.y;
    const int b  = bh / NH, h = bh % NH;

    for (int p = tid; p < 1024; p += 256)
        btab[p] = btab_g[(size_t)p * NH + h] * LOG2E;

    const int iw = i0 + iHalf * 32;
    bf16x8 qf[2][2];
#pragma unroll
    for (int it = 0; it < 2; ++it) {
        const short* qb = qh + ((size_t)bh * NSeq + iw + it * 16 + L) * HD + Q * 8;
        qf[it][0] = *(const bf16x8*)qb;
        qf[it][1] = *(const bf16x8*)(qb + 32);
    }

    size_t kgo[4], vgo[4];
    int lsl[4];
#pragma unroll
    for (int t = 0; t < 4; ++t) {
        int s = wave * 256 + t * 64 + lane;            // 0..1023
        int kr = s >> 3, kc = (s & 7) ^ (kr & 7);
        kgo[t] = ((size_t)bh * NSeq + kr) * HD + kc * 8;       // + j0*HD
        int vr = s >> 4, vc = (s & 15) ^ (vr & 15);
        vgo[t] = ((size_t)bh * HD + vr) * NSeq + vc * 8;       // + j0
        lsl[t] = s * 8;
    }

    const int i16g0 = b * 64 + blockIdx.x * 4 + iHalf * 2;
    const unsigned int* Ub[2] = {
        U + (size_t)i16g0 * 16 * 4 * 256 + lane * 4,
        U + ((size_t)i16g0 + 1) * 16 * 4 * 256 + lane * 4 };

    float lpart[2] = {0.0f, 0.0f};
    f32x4 accO[2][4];
#pragma unroll
    for (int it = 0; it < 2; ++it)
#pragma unroll
        for (int dt = 0; dt < 4; ++dt) accO[it][dt] = (f32x4){0.f, 0.f, 0.f, 0.f};

    const int swzB = (L & 7) << 4;      // XOR-16B chunk swizzle within 128B row

    for (int jt = 0; jt < 8; ++jt) {
        const int j0  = jt * 128;
        const int jt2 = jt * 2 + jHalf;        // 64-wide j-chunk index in U
        __syncthreads();
#pragma unroll
        for (int t = 0; t < 4; ++t) glds16(kh + kgo[t] + (size_t)j0 * HD, Ks + lsl[t]);
#pragma unroll
        for (int t = 0; t < 4; ++t) glds16(vt + vgo[t] + j0, Vs + lsl[t]);
        __syncthreads();

        // QK^T + bias + exp2 + P-write for both i-subtiles (kf shared)
#pragma unroll
        for (int nt = 0; nt < 4; ++nt) {
            const int r = jHalf * 64 + nt * 16 + L;
            bf16x8 kf0 = *(const bf16x8*)(Ks + (r * 8 + (Q ^ (L & 7))) * 8);
            bf16x8 kf1 = *(const bf16x8*)(Ks + (r * 8 + ((4 + Q) ^ (L & 7))) * 8);
#pragma unroll
            for (int it = 0; it < 2; ++it) {
                f32x4 z = (f32x4){0.f, 0.f, 0.f, 0.f};
                z = __builtin_amdgcn_mfma_f32_16x16x32_bf16(kf0, qf[it][0], z, 0, 0, 0);
                f32x4 st = __builtin_amdgcn_mfma_f32_16x16x32_bf16(kf1, qf[it][1], z, 0, 0, 0);

                uint4 u = *(const uint4*)(Ub[it] + ((size_t)jt2 * 4 + nt) * 256);
                const unsigned int uv[4] = {u.x, u.y, u.z, u.w};
                float pv[4];
                float ps = 0.0f;
#pragma unroll
                for (int reg = 0; reg < 4; ++reg) {
                    float arg = st[reg] + btab[uv[reg] & 1023];
                    arg = fmaf((float)(uv[reg] >> 16), EBDEC, arg);
                    float pe = EXP2F(arg);
                    ps += pe;
                    pv[reg] = pe;
                }
                lpart[it] += ps;
                unsigned p01 = pk2(pv[0], pv[1]);
                unsigned p23 = pk2(pv[2], pv[3]);
                char* pw = (char*)(&P[wave][it][0]) + L * 128
                         + ((nt * 32 + Q * 8) ^ swzB);
                *(uint2*)pw = make_uint2(p01, p23);
            }
        }

        // PV: vf shared across both i-subtiles
        bf16x8 pf0[2], pf1[2];
#pragma unroll
        for (int it = 0; it < 2; ++it) {
            const char* pb = (const char*)(&P[wave][it][0]) + L * 128;
            pf0[it] = *(const bf16x8*)(pb + ((Q * 16) ^ swzB));
            pf1[it] = *(const bf16x8*)(pb + (((4 + Q) * 16) ^ swzB));
        }
        __builtin_amdgcn_s_setprio(1);
#pragma unroll
        for (int dt = 0; dt < 4; ++dt) {
            int r = dt * 16 + L;
            bf16x8 vf0 = *(const bf16x8*)(Vs + (r * 16 + ((jHalf * 8 + Q) ^ L)) * 8);
            bf16x8 vf1 = *(const bf16x8*)(Vs + (r * 16 + ((jHalf * 8 + 4 + Q) ^ L)) * 8);
            accO[0][dt] = __builtin_amdgcn_mfma_f32_16x16x32_bf16(pf0[0], vf0, accO[0][dt], 0, 0, 0);
            accO[0][dt] = __builtin_amdgcn_mfma_f32_16x16x32_bf16(pf1[0], vf1, accO[0][dt], 0, 0, 0);
            accO[1][dt] = __builtin_amdgcn_mfma_f32_16x16x32_bf16(pf0[1], vf0, accO[1][dt], 0, 0, 0);
            accO[1][dt] = __builtin_amdgcn_mfma_f32_16x16x32_bf16(pf1[1], vf1, accO[1][dt], 0, 0, 0);
        }
        __builtin_amdgcn_s_setprio(0);
    }

    // ---- cross-jHalf reduction through the dead K/V buffers
    __syncthreads();
    float* Rac = (float*)Ks;    // [iHalf][it][dt][lane] f32x4 = 16 KB
    float* Rlp = (float*)Vs;    // [iHalf][it][lane] f32 = 1 KB
    if (jHalf == 1) {
#pragma unroll
        for (int it = 0; it < 2; ++it) {
#pragma unroll
            for (int dt = 0; dt < 4; ++dt)
                *(f32x4*)(Rac + (size_t)(((iHalf * 2 + it) * 4 + dt) * 64 + lane) * 4)
                    = accO[it][dt];
            Rlp[(iHalf * 2 + it) * 64 + lane] = lpart[it];
        }
    }
    __syncthreads();
    if (jHalf == 0) {
#pragma unroll
        for (int it = 0; it < 2; ++it) {
#pragma unroll
            for (int dt = 0; dt < 4; ++dt)
                accO[it][dt] += *(const f32x4*)(
                    Rac + (size_t)(((iHalf * 2 + it) * 4 + dt) * 64 + lane) * 4);
            float lp = lpart[it] + Rlp[(iHalf * 2 + it) * 64 + lane];
            lp += __shfl_xor(lp, 16, 64);
            lp += __shfl_xor(lp, 32, 64);
            float linv[4];
#pragma unroll
            for (int reg = 0; reg < 4; ++reg)
                linv[reg] = 1.0f / __shfl(lp, Q * 4 + reg, 64);
#pragma unroll
            for (int reg = 0; reg < 4; ++reg) {
                const size_t row = (size_t)b * NSeq + iw + it * 16 + Q * 4 + reg;
#pragma unroll
                for (int dt = 0; dt < 4; ++dt)
                    aout[row * DIM + h * HD + dt * 16 + L]
                        = f2b(accO[it][dt][reg] * linv[reg]);
            }
        }
    }
}

// ---------------------------------------------------------------------------
extern "C" void kernel_launch(void* const* d_in, const int* in_sizes, int n_in,
                              void* d_out, int out_size, void* d_ws, size_t ws_size,
                              hipStream_t stream)
{
    const float* x      = (const float*)d_in[0];
    const float* coords = (const float*)d_in[1];
    const float* elevp  = (const float*)d_in[2];
    const float* Wqkv   = (const float*)d_in[3];
    const float* Wproj  = (const float*)d_in[4];
    const float* bproj  = (const float*)d_in[5];
    const float* btab   = (const float*)d_in[6];
    const float* alpha  = (const float*)d_in[7];
    float* out = (float*)d_out;

    char* ws = (char*)d_ws;
    short* xb     = (short*)(ws);                        // 4096x768 bf16
    short* wqkvT  = (short*)(ws + 6291456);              // 2304x768 bf16
    short* wprojT = (short*)(ws + 9830400);              // 768x768 bf16
    short* qh     = (short*)(ws + 11010048);             // [48][1024][64]
    short* kh     = (short*)(ws + 17301504);
    short* vt     = (short*)(ws + 23592960);             // [48][64][1024]
    short* aout   = (short*)(ws + 29884416);             // 4096x768 bf16
    unsigned int* U = (unsigned int*)(ws + 36175872);    // 16.78 MB packed bias
    // total ws use: 52,953,088 bytes

    const int M = 4 * NSeq;

    prep_kernel<<<dim3(PREP_TOT), 256, 0, stream>>>(
        x, xb, Wqkv, wqkvT, Wproj, wprojT, coords, elevp, alpha, U);

    gemm_mfma<0><<<dim3(3 * DIM / 128, M / 64), 256, 0, stream>>>(
        xb, wqkvT, nullptr, nullptr, qh, kh, vt, M, 3 * DIM, DIM);

    attn_mfma<<<dim3(NSeq / 64, 4 * NH), 256, 0, stream>>>(
        qh, kh, vt, U, btab, aout);

    gemm_mfma<1><<<dim3(DIM / 128, M / 64), 256, 0, stream>>>(
        aout, wprojT, bproj, out, nullptr, nullptr, nullptr, M, DIM, DIM);
}

// Round 8
// 168.503 us; speedup vs baseline: 1.2631x; 1.0260x over previous
//
#include <hip/hip_runtime.h>
#include <hip/hip_bf16.h>
#include <math.h>

// Shapes: B=4, N=1024, D=768, H=12, hd=64
constexpr int NSeq = 1024;
constexpr int DIM  = 768;
constexpr int NH   = 12;
constexpr int HD   = 64;

// exp2-domain softmax constants (BSHIFT removed: softmax is shift-invariant;
// args stay in [-17,+3], p <= ~10, f32 row-sums are safe)
#define LOG2E     1.4426950408889634f
#define QSCALE    0.18033688011112042f   /* 0.125 * log2e */
#define EBQ       6551.278150676693f     /* log2e * 4541 (16-bit quant scale) */
#define EBDEC     (-1.0f / 4541.0f)

#if __has_builtin(__builtin_amdgcn_exp2f)
#define EXP2F(x) __builtin_amdgcn_exp2f(x)
#else
#define EXP2F(x) exp2f(x)
#endif

typedef __attribute__((ext_vector_type(8))) short bf16x8;   // 8 bf16 (4 VGPRs)
typedef __attribute__((ext_vector_type(4))) float f32x4;

// fp32 -> bf16 RNE (scalar)
__device__ __forceinline__ short f2b(float f) {
    unsigned u = __float_as_uint(f);
    unsigned r = (u + 0x7fffu + ((u >> 16) & 1u)) >> 16;
    return (short)r;
}
// packed pair via native v_cvt_pk_bf16_f32
__device__ __forceinline__ unsigned pk2(float a, float b) {
    __hip_bfloat162 h = __float22bfloat162_rn(float2{a, b});
    return *reinterpret_cast<unsigned*>(&h);
}

// async global->LDS, 16B per lane. LDS dest = uniform base + lane*16.
__device__ __forceinline__ void glds16(const short* g, short* l) {
    __builtin_amdgcn_global_load_lds(
        (const __attribute__((address_space(1))) void*)g,
        (__attribute__((address_space(3))) void*)l, 16, 0, 0);
}

// T5 bucket, integer-exact thresholds (validated round 1)
__device__ __forceinline__ int rel_bucket(int rel) {
    int n = -rel;
    int ret = (n < 0) ? 16 : 0;
    n = (n < 0) ? -n : n;
    int k;
    if (n < 8) {
        k = n;
    } else {
        k = 8 + (n >= 12) + (n >= 16) + (n >= 23) + (n >= 32)
              + (n >= 46) + (n >= 64) + (n >= 91);
        if (k > 15) k = 15;
    }
    return ret + k;
}

// ---------------------------------------------------------------------------
// Prep, R8: cast + weight transposes ONLY (3648 blocks). The upack section
// (U-table build) moved into gemm0's grid — it has no consumer until attn,
// so running it serially before gemm0 was pure exposed time.
constexpr int PREP_CAST = 3072;
constexpr int PREP_TOT  = PREP_CAST + 576;    // 3648

__global__ __launch_bounds__(256) void prep_kernel(
    const float* __restrict__ x, short* __restrict__ xb,
    const float* __restrict__ Wqkv, short* __restrict__ wqkvT,
    const float* __restrict__ Wproj, short* __restrict__ wprojT)
{
    __shared__ float t[32][33];
    const int bx  = blockIdx.x;
    const int tid = threadIdx.x;

    if (bx < PREP_CAST) {
        // ---- cast x -> bf16
        int i = (bx * 256 + tid) * 4;
        float4 v = *(const float4*)(x + i);
        *(short4*)(xb + i) = make_short4(f2b(v.x), f2b(v.y), f2b(v.z), f2b(v.w));
        return;
    }
    // ---- weight transposes: 4 tiles per block
    {
        const int bxx = bx - PREP_CAST;        // 0..575
#pragma unroll
        for (int tt = 0; tt < 4; ++tt) {
            const int tile = bxx * 4 + tt;     // 0..2303
            const float* W; short* WT; int K, Nw, idx;
            if (tile < 1728) { W = Wqkv;  WT = wqkvT;  K = DIM; Nw = 3 * DIM; idx = tile; }
            else             { W = Wproj; WT = wprojT; K = DIM; Nw = DIM;     idx = tile - 1728; }
            const int ntl = idx % (Nw / 32), ktl = idx / (Nw / 32);
            const int k0 = ktl * 32, n0 = ntl * 32;
            const int tx = tid & 31, ty = tid >> 5;
            __syncthreads();                   // WAR vs previous tile's reads
#pragma unroll
            for (int r = 0; r < 4; ++r)
                t[ty + r * 8][tx] = W[(size_t)(k0 + ty + r * 8) * Nw + n0 + tx];
            __syncthreads();
#pragma unroll
            for (int r = 0; r < 4; ++r)
                WT[(size_t)(n0 + ty + r * 8) * K + k0 + tx] = f2b(t[tx][ty + r * 8]);
        }
    }
}

// ---------------------------------------------------------------------------
// bf16 MFMA GEMM, 2-phase double-buffered (R7 form, best-so-far), with the
// upack U-table builder FUSED into the EPI=0 grid: blocks [0,1152) = gemm
// tiles (decode bx%18 / bx/18 == old 2D order), blocks [1152,3200) = upack
// (verbatim from old prep; no LDS, no barriers — whole-block uniform branch).
// Upack's VALU/VMEM work backfills CUs as gemm blocks retire (m114 overlap).
constexpr int G0_TILES = 18 * 64;             // 1152
constexpr int G0_UPACK = 2048;
constexpr int G0_GRID  = G0_TILES + G0_UPACK; // 3200

template <int EPI>
__global__ __launch_bounds__(256) void gemm_mfma(
    const short* __restrict__ A, const short* __restrict__ BT,
    const float* __restrict__ bias, float* __restrict__ Cout,
    short* __restrict__ qh, short* __restrict__ kh, short* __restrict__ vt,
    const float* __restrict__ coords, const float* __restrict__ elev,
    const float* __restrict__ alpha_p, unsigned int* __restrict__ U,
    int M, int N, int K)
{
    // [buf][As 4096 | Bs 8192] shorts; 2 x 12288 = 48 KB
    __shared__ short SH[2 * (64 * 64 + 128 * 64)];

    const int tid  = threadIdx.x;

    if (EPI == 0 && blockIdx.x >= G0_TILES) {
        // ---- fused upack: build packed bias table U (consumed by attn only)
        const int ub   = blockIdx.x - G0_TILES;   // 0..2047
        const int b    = ub >> 9;
        const int rem  = ub & 511;
        const int i16  = rem >> 3;
        const int jtp  = rem & 7;
        const int blk  = b * 64 + i16;
        const int lane = tid & 63, wv = tid >> 6;
        const int L = lane & 15, Q = lane >> 4;
        const float alpha = alpha_p[0];

        const int i = (i16 << 4) + L;
        const float2 cf = *(const float2*)&coords[(((size_t)b << 10) + i) * 2];
        const int cix = (int)(cf.x * 128.0f);
        const int ciy = (int)(cf.y * 128.0f);
        const float er = elev[((size_t)b << 10) + i];
        const int jt = jtp * 2 + (wv >> 1);
#pragma unroll
        for (int nth = 0; nth < 2; ++nth) {
            const int nt = (wv & 1) * 2 + nth;
            const int j0q = jt * 64 + nt * 16 + Q * 4;
            float4 c01 = *(const float4*)&coords[(((size_t)b << 10) + j0q) * 2];
            float4 c23 = *(const float4*)&coords[(((size_t)b << 10) + j0q + 2) * 2];
            float4 ej  = *(const float4*)&elev[((size_t)b << 10) + j0q];
            const float cjx[4] = {c01.x, c01.z, c23.x, c23.z};
            const float cjy[4] = {c01.y, c01.w, c23.y, c23.w};
            const float ejv[4] = {ej.x, ej.y, ej.z, ej.w};
            unsigned int uo[4];
#pragma unroll
            for (int reg = 0; reg < 4; ++reg) {
                int bk = rel_bucket(cix - (int)(cjx[reg] * 128.0f)) * 32
                       + rel_bucket(ciy - (int)(cjy[reg] * 128.0f));
                float ebp = fminf(10.0f,
                    fmaxf(0.0f, alpha * fmaxf((ejv[reg] - er) * 0.001f, 0.0f)));
                unsigned int q = (unsigned int)lrintf(ebp * EBQ);
                uo[reg] = (unsigned int)bk | (q << 16);
            }
            size_t base = ((((size_t)blk * 16 + jt) * 4 + nt) * 64 + lane) * 4;
            *(uint4*)(U + base) = make_uint4(uo[0], uo[1], uo[2], uo[3]);
        }
        return;
    }

    const int lane = tid & 63;
    const int wave = tid >> 6;
    const int L = lane & 15, Q = lane >> 4;
    int m0b, n0b;
    if (EPI == 0) {                       // 1D fused grid, x-fast like old 2D
        m0b = (blockIdx.x / 18) * 64;
        n0b = (blockIdx.x % 18) * 128;
    } else {
        m0b = blockIdx.y * 64;
        n0b = blockIdx.x * 128;
    }
    const int mw = (wave >> 1) * 32;
    const int nw = (wave & 1) * 64;

    size_t aoff[2]; int la[2];
#pragma unroll
    for (int t = 0; t < 2; ++t) {
        int s = wave * 128 + t * 64 + lane;
        int r = s >> 3, c = (s & 7) ^ (r & 7);
        aoff[t] = (size_t)(m0b + r) * K + c * 8;
        la[t] = (wave * 128 + t * 64) * 8;
    }
    size_t boff[4]; int lb[4];
#pragma unroll
    for (int t = 0; t < 4; ++t) {
        int s = wave * 256 + t * 64 + lane;
        int r = s >> 3, c = (s & 7) ^ (r & 7);
        boff[t] = (size_t)(n0b + r) * K + c * 8;
        lb[t] = (wave * 256 + t * 64) * 8;
    }

    f32x4 acc[2][4];
#pragma unroll
    for (int i = 0; i < 2; ++i)
#pragma unroll
        for (int j = 0; j < 4; ++j) acc[i][j] = (f32x4){0.f, 0.f, 0.f, 0.f};

    // prologue: stage tile 0 into buf 0
#pragma unroll
    for (int t = 0; t < 2; ++t) glds16(A + aoff[t], SH + la[t]);
#pragma unroll
    for (int t = 0; t < 4; ++t) glds16(BT + boff[t], SH + 4096 + lb[t]);
    __syncthreads();

    for (int k0 = 0; k0 < K; k0 += 64) {
        const int cur = (k0 >> 6) & 1;
        short* Asc = SH + cur * 12288;
        short* Bsc = Asc + 4096;

        // stage NEXT tile into the other buffer (issue-early; latency hides
        // under the compute below, drained by the end-of-iter barrier)
        if (k0 + 64 < K) {
            short* Asn = SH + (cur ^ 1) * 12288;
            short* Bsn = Asn + 4096;
#pragma unroll
            for (int t = 0; t < 2; ++t) glds16(A + aoff[t] + k0 + 64, Asn + la[t]);
#pragma unroll
            for (int t = 0; t < 4; ++t) glds16(BT + boff[t] + k0 + 64, Bsn + lb[t]);
        }

#pragma unroll
        for (int ks = 0; ks < 2; ++ks) {
            bf16x8 af[2], bfr[4];
#pragma unroll
            for (int mt = 0; mt < 2; ++mt) {
                int r = mw + mt * 16 + L;
                af[mt] = *(const bf16x8*)(Asc + (r * 8 + ((ks * 4 + Q) ^ (r & 7))) * 8);
            }
#pragma unroll
            for (int nt = 0; nt < 4; ++nt) {
                int r = nw + nt * 16 + L;
                bfr[nt] = *(const bf16x8*)(Bsc + (r * 8 + ((ks * 4 + Q) ^ (r & 7))) * 8);
            }
#pragma unroll
            for (int mt = 0; mt < 2; ++mt)
#pragma unroll
                for (int nt = 0; nt < 4; ++nt)
                    acc[mt][nt] = __builtin_amdgcn_mfma_f32_16x16x32_bf16(
                        af[mt], bfr[nt], acc[mt][nt], 0, 0, 0);
        }
        __syncthreads();   // drains next-tile stage (after compute) + WAR
    }

    const int m0 = m0b + mw, n0 = n0b + nw;
    if (EPI == 1) {
#pragma unroll
        for (int nt = 0; nt < 4; ++nt) {
            const int col = n0 + nt * 16 + L;
            const float bv = bias[col];
#pragma unroll
            for (int mt = 0; mt < 2; ++mt) {
                const int r0 = m0 + mt * 16 + Q * 4;
#pragma unroll
                for (int reg = 0; reg < 4; ++reg)
                    Cout[(size_t)(r0 + reg) * N + col] = acc[mt][nt][reg] + bv;
            }
        }
    } else {
        // ---- EPI=0: LDS-staged coalesced scatter (unchanged; T = SH).
        const int sec   = n0b / DIM;          // 0=Q, 1=K, 2=V
        const int hloc  = (n0b % DIM) >> 6;   // tile spans heads hloc, hloc+1
        const int bidx  = m0b >> 10;
        const int ntok0 = m0b & 1023;
        short* T = SH;
        // loop's final __syncthreads already ordered all K-loop LDS reads

        if (sec < 2) {
            // T[token][col], stride 136
            const float qs = (sec == 0) ? QSCALE : 1.0f;
#pragma unroll
            for (int nt = 0; nt < 4; ++nt)
#pragma unroll
                for (int mt = 0; mt < 2; ++mt) {
                    int tok = mw + mt * 16 + Q * 4;
                    int col = nw + nt * 16 + L;
#pragma unroll
                    for (int reg = 0; reg < 4; ++reg)
                        T[(tok + reg) * 136 + col] = f2b(acc[mt][nt][reg] * qs);
                }
            __syncthreads();
            const int pr = tid >> 1, half = tid & 1;
            const int hh = pr >> 6, tok = pr & 63;
            short* dstb = (sec == 0 ? qh : kh)
                + (((size_t)bidx * NH + hloc + hh) * NSeq + ntok0 + tok) * HD + half * 32;
            const short* srcb = T + tok * 136 + hh * 64 + half * 32;
#pragma unroll
            for (int c = 0; c < 4; ++c)
                *(bf16x8*)(dstb + c * 8) = *(const bf16x8*)(srcb + c * 8);
        } else {
            // V: T[col][token], stride 72; packed 8B frag writes
#pragma unroll
            for (int nt = 0; nt < 4; ++nt)
#pragma unroll
                for (int mt = 0; mt < 2; ++mt) {
                    int tok = mw + mt * 16 + Q * 4;
                    int col = nw + nt * 16 + L;
                    short4 pv = make_short4(f2b(acc[mt][nt][0]), f2b(acc[mt][nt][1]),
                                            f2b(acc[mt][nt][2]), f2b(acc[mt][nt][3]));
                    *(short4*)&T[col * 72 + tok] = pv;
                }
            __syncthreads();
            const int col = tid >> 1, half = tid & 1;
            const int hh = col >> 6, d = col & 63;
            short* dstb = vt
                + (((size_t)bidx * NH + hloc + hh) * HD + d) * NSeq + ntok0 + half * 32;
            const short* srcb = T + col * 72 + half * 32;
#pragma unroll
            for (int c = 0; c < 4; ++c)
                *(bf16x8*)(dstb + c * 8) = *(const bf16x8*)(srcb + c * 8);
        }
    }
}

// ---------------------------------------------------------------------------
// Transposed-S flash attention, v9 (R3-verified, 46.0 us): i-register-blocked
// 2x, conflict-minimal P layout (stride 128B + XOR(L&7) 16B-chunk swizzle),
// f32 btab, in-loop U loads, glds16 staging between two barriers.
// Reg-staging of K/V refuted twice (R2: VGPR dbuf spilled; R6: allocator put
// per-iter uint4 arrays in scratch, WRITE 6->178 MB). Do not re-attempt.
__global__ __launch_bounds__(256, 3) void attn_mfma(
    const short* __restrict__ qh, const short* __restrict__ kh,
    const short* __restrict__ vt,
    const unsigned int* __restrict__ U,
    const float* __restrict__ btab_g,             // [1024][12]
    short* __restrict__ aout)                     // [4096][768] bf16
{
    __shared__ short Ks[128 * 64];      // 16 KB, rows=j (128), 8 chunks/row
    __shared__ short Vs[64 * 128];      // 16 KB, rows=d (64), 16 chunks/row
    __shared__ float btab[1024];        // 4 KB (pre-scaled: *log2e)
    __shared__ short P[4][2][16 * 64];  // 16 KB: [wave][it][row L][64]

    const int tid   = threadIdx.x;
    const int lane  = tid & 63, wave = tid >> 6;
    const int iHalf = wave >> 1, jHalf = wave & 1;
    const int L = lane & 15, Q = lane >> 4;
    const int i0 = blockIdx.x * 64;
    const int bh = blockIdx.y;
    const int b  = bh / NH, h = bh % NH;

    for (int p = tid; p < 1024; p += 256)
        btab[p] = btab_g[(size_t)p * NH + h] * LOG2E;

    const int iw = i0 + iHalf * 32;
    bf16x8 qf[2][2];
#pragma unroll
    for (int it = 0; it < 2; ++it) {
        const short* qb = qh + ((size_t)bh * NSeq + iw + it * 16 + L) * HD + Q * 8;
        qf[it][0] = *(const bf16x8*)qb;
        qf[it][1] = *(const bf16x8*)(qb + 32);
    }

    size_t kgo[4], vgo[4];
    int lsl[4];
#pragma unroll
    for (int t = 0; t < 4; ++t) {
        int s = wave * 256 + t * 64 + lane;            // 0..1023
        int kr = s >> 3, kc = (s & 7) ^ (kr & 7);
        kgo[t] = ((size_t)bh * NSeq + kr) * HD + kc * 8;       // + j0*HD
        int vr = s >> 4, vc = (s & 15) ^ (vr & 15);
        vgo[t] = ((size_t)bh * HD + vr) * NSeq + vc * 8;       // + j0
        lsl[t] = s * 8;
    }

    const int i16g0 = b * 64 + blockIdx.x * 4 + iHalf * 2;
    const unsigned int* Ub[2] = {
        U + (size_t)i16g0 * 16 * 4 * 256 + lane * 4,
        U + ((size_t)i16g0 + 1) * 16 * 4 * 256 + lane * 4 };

    float lpart[2] = {0.0f, 0.0f};
    f32x4 accO[2][4];
#pragma unroll
    for (int it = 0; it < 2; ++it)
#pragma unroll
        for (int dt = 0; dt < 4; ++dt) accO[it][dt] = (f32x4){0.f, 0.f, 0.f, 0.f};

    const int swzB = (L & 7) << 4;      // XOR-16B chunk swizzle within 128B row

    for (int jt = 0; jt < 8; ++jt) {
        const int j0  = jt * 128;
        const int jt2 = jt * 2 + jHalf;        // 64-wide j-chunk index in U
        __syncthreads();
#pragma unroll
        for (int t = 0; t < 4; ++t) glds16(kh + kgo[t] + (size_t)j0 * HD, Ks + lsl[t]);
#pragma unroll
        for (int t = 0; t < 4; ++t) glds16(vt + vgo[t] + j0, Vs + lsl[t]);
        __syncthreads();

        // QK^T + bias + exp2 + P-write for both i-subtiles (kf shared)
#pragma unroll
        for (int nt = 0; nt < 4; ++nt) {
            const int r = jHalf * 64 + nt * 16 + L;
            bf16x8 kf0 = *(const bf16x8*)(Ks + (r * 8 + (Q ^ (L & 7))) * 8);
            bf16x8 kf1 = *(const bf16x8*)(Ks + (r * 8 + ((4 + Q) ^ (L & 7))) * 8);
#pragma unroll
            for (int it = 0; it < 2; ++it) {
                f32x4 z = (f32x4){0.f, 0.f, 0.f, 0.f};
                z = __builtin_amdgcn_mfma_f32_16x16x32_bf16(kf0, qf[it][0], z, 0, 0, 0);
                f32x4 st = __builtin_amdgcn_mfma_f32_16x16x32_bf16(kf1, qf[it][1], z, 0, 0, 0);

                uint4 u = *(const uint4*)(Ub[it] + ((size_t)jt2 * 4 + nt) * 256);
                const unsigned int uv[4] = {u.x, u.y, u.z, u.w};
                float pv[4];
                float ps = 0.0f;
#pragma unroll
                for (int reg = 0; reg < 4; ++reg) {
                    float arg = st[reg] + btab[uv[reg] & 1023];
                    arg = fmaf((float)(uv[reg] >> 16), EBDEC, arg);
                    float pe = EXP2F(arg);
                    ps += pe;
                    pv[reg] = pe;
                }
                lpart[it] += ps;
                unsigned p01 = pk2(pv[0], pv[1]);
                unsigned p23 = pk2(pv[2], pv[3]);
                char* pw = (char*)(&P[wave][it][0]) + L * 128
                         + ((nt * 32 + Q * 8) ^ swzB);
                *(uint2*)pw = make_uint2(p01, p23);
            }
        }

        // PV: vf shared across both i-subtiles
        bf16x8 pf0[2], pf1[2];
#pragma unroll
        for (int it = 0; it < 2; ++it) {
            const char* pb = (const char*)(&P[wave][it][0]) + L * 128;
            pf0[it] = *(const bf16x8*)(pb + ((Q * 16) ^ swzB));
            pf1[it] = *(const bf16x8*)(pb + (((4 + Q) * 16) ^ swzB));
        }
        __builtin_amdgcn_s_setprio(1);
#pragma unroll
        for (int dt = 0; dt < 4; ++dt) {
            int r = dt * 16 + L;
            bf16x8 vf0 = *(const bf16x8*)(Vs + (r * 16 + ((jHalf * 8 + Q) ^ L)) * 8);
            bf16x8 vf1 = *(const bf16x8*)(Vs + (r * 16 + ((jHalf * 8 + 4 + Q) ^ L)) * 8);
            accO[0][dt] = __builtin_amdgcn_mfma_f32_16x16x32_bf16(pf0[0], vf0, accO[0][dt], 0, 0, 0);
            accO[0][dt] = __builtin_amdgcn_mfma_f32_16x16x32_bf16(pf1[0], vf1, accO[0][dt], 0, 0, 0);
            accO[1][dt] = __builtin_amdgcn_mfma_f32_16x16x32_bf16(pf0[1], vf0, accO[1][dt], 0, 0, 0);
            accO[1][dt] = __builtin_amdgcn_mfma_f32_16x16x32_bf16(pf1[1], vf1, accO[1][dt], 0, 0, 0);
        }
        __builtin_amdgcn_s_setprio(0);
    }

    // ---- cross-jHalf reduction through the dead K/V buffers
    __syncthreads();
    float* Rac = (float*)Ks;    // [iHalf][it][dt][lane] f32x4 = 16 KB
    float* Rlp = (float*)Vs;    // [iHalf][it][lane] f32 = 1 KB
    if (jHalf == 1) {
#pragma unroll
        for (int it = 0; it < 2; ++it) {
#pragma unroll
            for (int dt = 0; dt < 4; ++dt)
                *(f32x4*)(Rac + (size_t)(((iHalf * 2 + it) * 4 + dt) * 64 + lane) * 4)
                    = accO[it][dt];
            Rlp[(iHalf * 2 + it) * 64 + lane] = lpart[it];
        }
    }
    __syncthreads();
    if (jHalf == 0) {
#pragma unroll
        for (int it = 0; it < 2; ++it) {
#pragma unroll
            for (int dt = 0; dt < 4; ++dt)
                accO[it][dt] += *(const f32x4*)(
                    Rac + (size_t)(((iHalf * 2 + it) * 4 + dt) * 64 + lane) * 4);
            float lp = lpart[it] + Rlp[(iHalf * 2 + it) * 64 + lane];
            lp += __shfl_xor(lp, 16, 64);
            lp += __shfl_xor(lp, 32, 64);
            float linv[4];
#pragma unroll
            for (int reg = 0; reg < 4; ++reg)
                linv[reg] = 1.0f / __shfl(lp, Q * 4 + reg, 64);
#pragma unroll
            for (int reg = 0; reg < 4; ++reg) {
                const size_t row = (size_t)b * NSeq + iw + it * 16 + Q * 4 + reg;
#pragma unroll
                for (int dt = 0; dt < 4; ++dt)
                    aout[row * DIM + h * HD + dt * 16 + L]
                        = f2b(accO[it][dt][reg] * linv[reg]);
            }
        }
    }
}

// ---------------------------------------------------------------------------
extern "C" void kernel_launch(void* const* d_in, const int* in_sizes, int n_in,
                              void* d_out, int out_size, void* d_ws, size_t ws_size,
                              hipStream_t stream)
{
    const float* x      = (const float*)d_in[0];
    const float* coords = (const float*)d_in[1];
    const float* elevp  = (const float*)d_in[2];
    const float* Wqkv   = (const float*)d_in[3];
    const float* Wproj  = (const float*)d_in[4];
    const float* bproj  = (const float*)d_in[5];
    const float* btab   = (const float*)d_in[6];
    const float* alpha  = (const float*)d_in[7];
    float* out = (float*)d_out;

    char* ws = (char*)d_ws;
    short* xb     = (short*)(ws);                        // 4096x768 bf16
    short* wqkvT  = (short*)(ws + 6291456);              // 2304x768 bf16
    short* wprojT = (short*)(ws + 9830400);              // 768x768 bf16
    short* qh     = (short*)(ws + 11010048);             // [48][1024][64]
    short* kh     = (short*)(ws + 17301504);
    short* vt     = (short*)(ws + 23592960);             // [48][64][1024]
    short* aout   = (short*)(ws + 29884416);             // 4096x768 bf16
    unsigned int* U = (unsigned int*)(ws + 36175872);    // 16.78 MB packed bias
    // total ws use: 52,953,088 bytes

    const int M = 4 * NSeq;

    prep_kernel<<<dim3(PREP_TOT), 256, 0, stream>>>(
        x, xb, Wqkv, wqkvT, Wproj, wprojT);

    gemm_mfma<0><<<dim3(G0_GRID), 256, 0, stream>>>(
        xb, wqkvT, nullptr, nullptr, qh, kh, vt,
        coords, elevp, alpha, U, M, 3 * DIM, DIM);

    attn_mfma<<<dim3(NSeq / 64, 4 * NH), 256, 0, stream>>>(
        qh, kh, vt, U, btab, aout);

    gemm_mfma<1><<<dim3(DIM / 128, M / 64), 256, 0, stream>>>(
        aout, wprojT, bproj, out, nullptr, nullptr, nullptr,
        nullptr, nullptr, nullptr, nullptr, M, DIM, DIM);
}